// Round 10
// baseline (92.197 us; speedup 1.0000x reference)
//
#include <hip/hip_runtime.h>
#include <hip/hip_bf16.h>

#define N_NODES 10000
#define M_PAD   10112          // 158 * 64
#define DIM     256
#define HID     512
#define KDIM    512            // K for both GEMMs (2*DIM == HID == 512)
#define N_EDGE  320000
#define ELL_W   128            // max degree capacity (mean 32, sigma 5.7)

typedef __attribute__((ext_vector_type(4))) float  f32x4;
typedef __attribute__((ext_vector_type(8))) __bf16 bf16x8;

// round-to-nearest-even f32 -> bf16 bits
__device__ __forceinline__ unsigned short f2bf(float f) {
    union { float f; unsigned int u; } v; v.f = f;
    unsigned int r = v.u + 0x7FFFu + ((v.u >> 16) & 1u);
    return (unsigned short)(r >> 16);
}
// bf16 bits -> f32 (exact)
__device__ __forceinline__ float bf2f(unsigned short u) {
    union { unsigned int i; float f; } v; v.i = ((unsigned int)u) << 16;
    return v.f;
}

// ---------------------------------------------------------------------------
// zero deg[0..10240)
// ---------------------------------------------------------------------------
__global__ void k_zero(int* __restrict__ deg) {
    int i = blockIdx.x * 256 + threadIdx.x;
    if (i < 10240) deg[i] = 0;
}

// ---------------------------------------------------------------------------
// Fused prep: blockIdx ranges dispatch 4 independent jobs
//   [0,1250)      : ELL scatter  ell[d][slot] = (src, val)   (slot via atomic)
//   [1250,3750)   : cat[n][0..255] = bf16(x[n][*])
//   [3750,4774)   : Wct = bf16(Wc^T)
//   [4774,5798)   : W1t = bf16(W1^T)
// ---------------------------------------------------------------------------
__global__ void k_prep(const int* __restrict__ esrc, const int* __restrict__ edst,
                       const float* __restrict__ eval,
                       int* __restrict__ deg, int2* __restrict__ ell,
                       const float* __restrict__ x, unsigned short* __restrict__ cat,
                       const float* __restrict__ Wc, unsigned short* __restrict__ Wct,
                       const float* __restrict__ W1, unsigned short* __restrict__ W1t) {
    int b = blockIdx.x;
    if (b < 1250) {
        int e = b * 256 + threadIdx.x;
        if (e < N_EDGE) {
            int d = edst[e];
            int slot = atomicAdd(&deg[d], 1);
            if (slot < ELL_W)   // safety clamp; never triggers for this input
                ell[(size_t)d * ELL_W + slot] = make_int2(esrc[e], __float_as_int(eval[e]));
        }
    } else if (b < 3750) {
        int t  = (b - 1250) * 256 + threadIdx.x;   // < 640000 exactly
        int n  = t >> 6;
        int c4 = (t & 63) * 4;
        f32x4 v = *(const f32x4*)(x + (size_t)n * DIM + c4);
        ushort4 o;
        o.x = f2bf(v.x); o.y = f2bf(v.y); o.z = f2bf(v.z); o.w = f2bf(v.w);
        *(ushort4*)(cat + (size_t)n * 2 * DIM + c4) = o;
    } else if (b < 4774) {
        int t = (b - 3750) * 256 + threadIdx.x;
        int k = t >> 9, n = t & 511;
        Wct[(size_t)n * 512 + k] = f2bf(Wc[(size_t)k * 512 + n]);
    } else {
        int t = (b - 4774) * 256 + threadIdx.x;
        int k = t >> 9, n = t & 511;
        W1t[(size_t)n * 512 + k] = f2bf(W1[(size_t)k * 512 + n]);
    }
}

// ---------------------------------------------------------------------------
// Aggregate: one wave per node. Lane l preloads ELL record l (coalesced 8B),
// readlane-broadcasts it; 4 row gathers in flight into 4 accumulators.
// ---------------------------------------------------------------------------
__global__ void k_agg(const int* __restrict__ deg, const int2* __restrict__ ell,
                      unsigned short* __restrict__ cat) {
    int wid  = (blockIdx.x * blockDim.x + threadIdx.x) >> 6;
    int lane = threadIdx.x & 63;
    if (wid >= N_NODES) return;
    int cnt = deg[wid];
    if (cnt > ELL_W) cnt = ELL_W;
    const int2* row = ell + (size_t)wid * ELL_W;
    int c4 = lane * 4;
    f32x4 a0 = {0.f,0.f,0.f,0.f}, a1 = a0, a2 = a0, a3 = a0;
    for (int base = 0; base < cnt; base += 64) {
        int m = cnt - base;
        if (m > 64) m = 64;
        int2 my = make_int2(0, 0);
        if (lane < m) my = row[base + lane];
        int j = 0;
        for (; j + 4 <= m; j += 4) {
            int   s0 = __builtin_amdgcn_readlane(my.x, j);
            float v0 = __int_as_float(__builtin_amdgcn_readlane(my.y, j));
            int   s1 = __builtin_amdgcn_readlane(my.x, j + 1);
            float v1 = __int_as_float(__builtin_amdgcn_readlane(my.y, j + 1));
            int   s2 = __builtin_amdgcn_readlane(my.x, j + 2);
            float v2 = __int_as_float(__builtin_amdgcn_readlane(my.y, j + 2));
            int   s3 = __builtin_amdgcn_readlane(my.x, j + 3);
            float v3 = __int_as_float(__builtin_amdgcn_readlane(my.y, j + 3));
            ushort4 q0 = *(const ushort4*)(cat + (size_t)s0 * 2 * DIM + c4);
            ushort4 q1 = *(const ushort4*)(cat + (size_t)s1 * 2 * DIM + c4);
            ushort4 q2 = *(const ushort4*)(cat + (size_t)s2 * 2 * DIM + c4);
            ushort4 q3 = *(const ushort4*)(cat + (size_t)s3 * 2 * DIM + c4);
            a0.x += v0 * bf2f(q0.x); a0.y += v0 * bf2f(q0.y);
            a0.z += v0 * bf2f(q0.z); a0.w += v0 * bf2f(q0.w);
            a1.x += v1 * bf2f(q1.x); a1.y += v1 * bf2f(q1.y);
            a1.z += v1 * bf2f(q1.z); a1.w += v1 * bf2f(q1.w);
            a2.x += v2 * bf2f(q2.x); a2.y += v2 * bf2f(q2.y);
            a2.z += v2 * bf2f(q2.z); a2.w += v2 * bf2f(q2.w);
            a3.x += v3 * bf2f(q3.x); a3.y += v3 * bf2f(q3.y);
            a3.z += v3 * bf2f(q3.z); a3.w += v3 * bf2f(q3.w);
        }
        for (; j < m; ++j) {
            int   s0 = __builtin_amdgcn_readlane(my.x, j);
            float v0 = __int_as_float(__builtin_amdgcn_readlane(my.y, j));
            ushort4 q0 = *(const ushort4*)(cat + (size_t)s0 * 2 * DIM + c4);
            a0.x += v0 * bf2f(q0.x); a0.y += v0 * bf2f(q0.y);
            a0.z += v0 * bf2f(q0.z); a0.w += v0 * bf2f(q0.w);
        }
    }
    ushort4 o;
    o.x = f2bf((a0.x + a1.x) + (a2.x + a3.x));
    o.y = f2bf((a0.y + a1.y) + (a2.y + a3.y));
    o.z = f2bf((a0.z + a1.z) + (a2.z + a3.z));
    o.w = f2bf((a0.w + a1.w) + (a2.w + a3.w));
    *(ushort4*)(cat + (size_t)wid * 2 * DIM + DIM + c4) = o;
}

// ---------------------------------------------------------------------------
// LDS-tiled GEMM, 64x128 tile per block (BM=64, BN=128, BK=64), 4 waves
// (2Mx2N, 32x64 each), double-buffered LDS, one barrier per K-step.
// Grid 632 = 158 M-tiles x 4 N-tiles, XCD-swizzled (632 % 8 == 0).
// 55 KB LDS -> 2 blocks/CU co-resident (TLP hides load latency).
// MODE 0: relu(acc+bias) -> bf16 hout.
// MODE 1: prelu(acc+bias) dot w2, column-reduced -> part[8][M_PAD] (fused GEMV).
// ---------------------------------------------------------------------------
#define LDSW 72   // 64 + 8 pad, elements

template <int MODE>
__global__ __launch_bounds__(256)
void k_gemm64(const unsigned short* __restrict__ A,
              const unsigned short* __restrict__ Bt,
              const float* __restrict__ bias,
              const float* __restrict__ pa,
              const float* __restrict__ w2,
              unsigned short* __restrict__ hout,
              float* __restrict__ part) {
    __shared__ unsigned short As[2][64 * LDSW];
    __shared__ unsigned short Bs[2][128 * LDSW];

    const int t    = threadIdx.x;
    const int lane = t & 63;
    const int w    = t >> 6;
    const int wr   = w >> 1, wc = w & 1;

    // XCD-aware bijective swizzle: 632 blocks = 8 XCDs x 79
    const int bid = blockIdx.x;
    const int swz = (bid & 7) * 79 + (bid >> 3);
    const int tn  = swz & 3;                  // 4 N-tiles of 128
    const int tm  = swz >> 2;                 // 158 M-tiles of 64
    const int gm0 = tm * 64, gn0 = tn * 128;

    // staging maps (BK=64 cols):
    //   A: thread t -> row t>>2 (64 rows), colseg (t&3)*16, 32 B
    //   B: thread t -> row t>>1 (128 rows), colseg (t&1)*32, 64 B
    const int arow = t >> 2, acol = (t & 3) * 16;
    const int brow = t >> 1, bcol = (t & 1) * 32;
    const unsigned short* gA = A  + (size_t)(gm0 + arow) * KDIM + acol;
    const unsigned short* gB = Bt + (size_t)(gn0 + brow) * KDIM + bcol;
    const int woffA = arow * LDSW + acol;
    const int woffB = brow * LDSW + bcol;

    const int r15 = lane & 15;
    const int kf  = (lane >> 4) * 8;

    f32x4 acc[2][4] = {};
    f32x4 va[2], vb[4];

    va[0] = *(const f32x4*)(gA);
    va[1] = *(const f32x4*)(gA + 8);
    vb[0] = *(const f32x4*)(gB);
    vb[1] = *(const f32x4*)(gB + 8);
    vb[2] = *(const f32x4*)(gB + 16);
    vb[3] = *(const f32x4*)(gB + 24);
    *(f32x4*)&As[0][woffA]      = va[0];
    *(f32x4*)&As[0][woffA + 8]  = va[1];
    *(f32x4*)&Bs[0][woffB]      = vb[0];
    *(f32x4*)&Bs[0][woffB + 8]  = vb[1];
    *(f32x4*)&Bs[0][woffB + 16] = vb[2];
    *(f32x4*)&Bs[0][woffB + 24] = vb[3];
    __syncthreads();                          // buf0 ready

    #pragma unroll
    for (int ks = 0; ks < 8; ++ks) {
        const int cur = ks & 1;
        if (ks < 7) {                         // next tile's loads fly under MFMAs
            gA += 64; gB += 64;
            va[0] = *(const f32x4*)(gA);
            va[1] = *(const f32x4*)(gA + 8);
            vb[0] = *(const f32x4*)(gB);
            vb[1] = *(const f32x4*)(gB + 8);
            vb[2] = *(const f32x4*)(gB + 16);
            vb[3] = *(const f32x4*)(gB + 24);
        }
        #pragma unroll
        for (int kk = 0; kk < 2; ++kk) {
            bf16x8 af[2], bf[4];
            #pragma unroll
            for (int m = 0; m < 2; ++m)
                af[m] = *(const bf16x8*)&As[cur][(wr * 32 + m * 16 + r15) * LDSW + kk * 32 + kf];
            #pragma unroll
            for (int n = 0; n < 4; ++n)
                bf[n] = *(const bf16x8*)&Bs[cur][(wc * 64 + n * 16 + r15) * LDSW + kk * 32 + kf];
            #pragma unroll
            for (int m = 0; m < 2; ++m)
                #pragma unroll
                for (int n = 0; n < 4; ++n)
                    acc[m][n] = __builtin_amdgcn_mfma_f32_16x16x32_bf16(af[m], bf[n], acc[m][n], 0, 0, 0);
        }
        if (ks < 7) {                         // write next tile to the OTHER buf
            *(f32x4*)&As[cur ^ 1][woffA]      = va[0];
            *(f32x4*)&As[cur ^ 1][woffA + 8]  = va[1];
            *(f32x4*)&Bs[cur ^ 1][woffB]      = vb[0];
            *(f32x4*)&Bs[cur ^ 1][woffB + 8]  = vb[1];
            *(f32x4*)&Bs[cur ^ 1][woffB + 16] = vb[2];
            *(f32x4*)&Bs[cur ^ 1][woffB + 24] = vb[3];
            __syncthreads();                  // next buf ready (prev reads done)
        }
    }

    const int rq = lane >> 4;                // C row quad
    if (MODE == 0) {
        #pragma unroll
        for (int n = 0; n < 4; ++n) {
            int c = gn0 + wc * 64 + n * 16 + r15;
            float b = bias[c];
            #pragma unroll
            for (int m = 0; m < 2; ++m) {
                #pragma unroll
                for (int i = 0; i < 4; ++i) {
                    int row = gm0 + wr * 32 + m * 16 + rq * 4 + i;
                    float v = acc[m][n][i] + b;
                    v = v > 0.f ? v : 0.f;   // NaN/garbage from pad rows -> 0
                    hout[(size_t)row * HID + c] = f2bf(v);
                }
            }
        }
    } else {
        float rsum[2][4] = {};
        #pragma unroll
        for (int n = 0; n < 4; ++n) {
            int c = gn0 + wc * 64 + n * 16 + r15;
            float b = bias[c];
            float a = pa[c];
            float wv = w2[c];
            #pragma unroll
            for (int m = 0; m < 2; ++m)
                #pragma unroll
                for (int i = 0; i < 4; ++i) {
                    float v = acc[m][n][i] + b;
                    v = v > 0.f ? v : a * v;
                    rsum[m][i] += v * wv;
                }
        }
        // reduce over the 16 column-lanes; lane&15==0 holds the sum
        #pragma unroll
        for (int m = 0; m < 2; ++m)
            #pragma unroll
            for (int i = 0; i < 4; ++i) {
                float s = rsum[m][i];
                s += __shfl_xor(s, 1);
                s += __shfl_xor(s, 2);
                s += __shfl_xor(s, 4);
                s += __shfl_xor(s, 8);
                if (r15 == 0) {
                    int row = gm0 + wr * 32 + m * 16 + rq * 4 + i;
                    part[(size_t)(tn * 2 + wc) * M_PAD + row] = s;
                }
            }
    }
}

// ---------------------------------------------------------------------------
// pred[row] = sum_j part[j][row] + b2
// ---------------------------------------------------------------------------
__global__ void k_vout(const float* __restrict__ part, const float* __restrict__ b2,
                       float* __restrict__ pred) {
    int row = blockIdx.x * blockDim.x + threadIdx.x;
    if (row >= N_NODES) return;
    float s = b2[0];
    #pragma unroll
    for (int j = 0; j < 8; ++j) s += part[(size_t)j * M_PAD + row];
    pred[row] = s;
}

extern "C" void kernel_launch(void* const* d_in, const int* in_sizes, int n_in,
                              void* d_out, int out_size, void* d_ws, size_t ws_size,
                              hipStream_t stream) {
    const float* x    = (const float*)d_in[0];
    const int*   esrc = (const int*)  d_in[1];
    const int*   edst = (const int*)  d_in[2];
    const float* eval = (const float*)d_in[3];
    const float* Wc   = (const float*)d_in[4];
    const float* bc   = (const float*)d_in[5];
    const float* W1   = (const float*)d_in[6];
    const float* b1   = (const float*)d_in[7];
    const float* pa   = (const float*)d_in[8];
    const float* W2   = (const float*)d_in[9];
    const float* b2   = (const float*)d_in[10];
    float* pred = (float*)d_out;

    // workspace layout (16B-aligned), total ~32.6 MB
    char* w = (char*)d_ws;
    int*            deg   = (int*)w;                               //     40,960 B
    int2*           ell   = (int2*)(w + 40960);                    // 10,485,760 B (10240 x 128 x 8)
    unsigned short* cat   = (unsigned short*)(w + 10526720);       // 10,354,688 B (M_PAD x 512)
    unsigned short* Wct   = (unsigned short*)(w + 20881408);       //    524,288 B
    unsigned short* W1t   = (unsigned short*)(w + 21405696);       //    524,288 B
    unsigned short* h     = (unsigned short*)(w + 21929984);       // 10,354,688 B (M_PAD x 512)
    float*          partb = (float*)(w + 32284672);                //    323,584 B (8 x M_PAD)

    // ---- zero slot counters ----
    k_zero<<<40, 256, 0, stream>>>(deg);

    // ---- fused prep (ELL scatter + cat_x + both weight transposes) ----
    k_prep<<<5798, 256, 0, stream>>>(esrc, edst, eval, deg, ell, x, cat, Wc, Wct, W1, W1t);

    // ---- gather-aggregate into cat second half ----
    k_agg<<<(N_NODES * 64 + 255) / 256, 256, 0, stream>>>(deg, ell, cat);

    // ---- tiled GEMMs: 158 M-tiles x 4 N-tiles = 632 blocks (XCD-swizzled) ----
    k_gemm64<0><<<632, 256, 0, stream>>>(cat, Wct, bc, nullptr, nullptr, h, nullptr);
    k_gemm64<1><<<632, 256, 0, stream>>>(h, W1t, b1, pa, W2, nullptr, partb);

    // ---- final partial reduce ----
    k_vout<<<(N_NODES + 255) / 256, 256, 0, stream>>>(partb, b2, pred);
}

// Round 11
// 90.839 us; speedup vs baseline: 1.0149x; 1.0149x over previous
//
#include <hip/hip_runtime.h>
#include <hip/hip_bf16.h>

#define N_NODES 10000
#define M_PAD   10112          // 79 * 128
#define DIM     256
#define HID     512
#define KDIM    512            // K for both GEMMs (2*DIM == HID == 512)
#define N_EDGE  320000
#define ELL_W   128            // max degree capacity (mean 32, sigma 5.7)

typedef __attribute__((ext_vector_type(4))) float  f32x4;
typedef __attribute__((ext_vector_type(8))) __bf16 bf16x8;

// round-to-nearest-even f32 -> bf16 bits
__device__ __forceinline__ unsigned short f2bf(float f) {
    union { float f; unsigned int u; } v; v.f = f;
    unsigned int r = v.u + 0x7FFFu + ((v.u >> 16) & 1u);
    return (unsigned short)(r >> 16);
}
// bf16 bits -> f32 (exact)
__device__ __forceinline__ float bf2f(unsigned short u) {
    union { unsigned int i; float f; } v; v.i = ((unsigned int)u) << 16;
    return v.f;
}

// ---------------------------------------------------------------------------
// zero deg[0..10240)
// ---------------------------------------------------------------------------
__global__ void k_zero(int* __restrict__ deg) {
    int i = blockIdx.x * 256 + threadIdx.x;
    if (i < 10240) deg[i] = 0;
}

// ---------------------------------------------------------------------------
// Fused prep: blockIdx ranges dispatch 4 independent jobs
//   [0,1250)      : ELL scatter  ell[d][slot] = (src, val)   (slot via atomic)
//   [1250,3750)   : cat[n][0..255] = bf16(x[n][*])
//   [3750,4774)   : Wct = bf16(Wc^T)
//   [4774,5798)   : W1t = bf16(W1^T)
// ---------------------------------------------------------------------------
__global__ void k_prep(const int* __restrict__ esrc, const int* __restrict__ edst,
                       const float* __restrict__ eval,
                       int* __restrict__ deg, int2* __restrict__ ell,
                       const float* __restrict__ x, unsigned short* __restrict__ cat,
                       const float* __restrict__ Wc, unsigned short* __restrict__ Wct,
                       const float* __restrict__ W1, unsigned short* __restrict__ W1t) {
    int b = blockIdx.x;
    if (b < 1250) {
        int e = b * 256 + threadIdx.x;
        if (e < N_EDGE) {
            int d = edst[e];
            int slot = atomicAdd(&deg[d], 1);
            if (slot < ELL_W)   // safety clamp; never triggers for this input
                ell[(size_t)d * ELL_W + slot] = make_int2(esrc[e], __float_as_int(eval[e]));
        }
    } else if (b < 3750) {
        int t  = (b - 1250) * 256 + threadIdx.x;   // < 640000 exactly
        int n  = t >> 6;
        int c4 = (t & 63) * 4;
        f32x4 v = *(const f32x4*)(x + (size_t)n * DIM + c4);
        ushort4 o;
        o.x = f2bf(v.x); o.y = f2bf(v.y); o.z = f2bf(v.z); o.w = f2bf(v.w);
        *(ushort4*)(cat + (size_t)n * 2 * DIM + c4) = o;
    } else if (b < 4774) {
        int t = (b - 3750) * 256 + threadIdx.x;
        int k = t >> 9, n = t & 511;
        Wct[(size_t)n * 512 + k] = f2bf(Wc[(size_t)k * 512 + n]);
    } else {
        int t = (b - 4774) * 256 + threadIdx.x;
        int k = t >> 9, n = t & 511;
        W1t[(size_t)n * 512 + k] = f2bf(W1[(size_t)k * 512 + n]);
    }
}

// ---------------------------------------------------------------------------
// Aggregate: one wave per node. Lane l preloads ELL record l (coalesced 8B),
// readlane-broadcasts it; 8 row gathers in flight into 8 accumulators.
// ---------------------------------------------------------------------------
__global__ void k_agg(const int* __restrict__ deg, const int2* __restrict__ ell,
                      unsigned short* __restrict__ cat) {
    int wid  = (blockIdx.x * blockDim.x + threadIdx.x) >> 6;
    int lane = threadIdx.x & 63;
    if (wid >= N_NODES) return;
    int cnt = deg[wid];
    if (cnt > ELL_W) cnt = ELL_W;
    const int2* row = ell + (size_t)wid * ELL_W;
    int c4 = lane * 4;
    f32x4 a0 = {0.f,0.f,0.f,0.f}, a1 = a0, a2 = a0, a3 = a0;
    f32x4 a4 = a0, a5 = a0, a6 = a0, a7 = a0;
    for (int base = 0; base < cnt; base += 64) {
        int m = cnt - base;
        if (m > 64) m = 64;
        int2 my = make_int2(0, 0);
        if (lane < m) my = row[base + lane];
        int j = 0;
        for (; j + 8 <= m; j += 8) {
            int   s0 = __builtin_amdgcn_readlane(my.x, j);
            float v0 = __int_as_float(__builtin_amdgcn_readlane(my.y, j));
            int   s1 = __builtin_amdgcn_readlane(my.x, j + 1);
            float v1 = __int_as_float(__builtin_amdgcn_readlane(my.y, j + 1));
            int   s2 = __builtin_amdgcn_readlane(my.x, j + 2);
            float v2 = __int_as_float(__builtin_amdgcn_readlane(my.y, j + 2));
            int   s3 = __builtin_amdgcn_readlane(my.x, j + 3);
            float v3 = __int_as_float(__builtin_amdgcn_readlane(my.y, j + 3));
            int   s4 = __builtin_amdgcn_readlane(my.x, j + 4);
            float v4 = __int_as_float(__builtin_amdgcn_readlane(my.y, j + 4));
            int   s5 = __builtin_amdgcn_readlane(my.x, j + 5);
            float v5 = __int_as_float(__builtin_amdgcn_readlane(my.y, j + 5));
            int   s6 = __builtin_amdgcn_readlane(my.x, j + 6);
            float v6 = __int_as_float(__builtin_amdgcn_readlane(my.y, j + 6));
            int   s7 = __builtin_amdgcn_readlane(my.x, j + 7);
            float v7 = __int_as_float(__builtin_amdgcn_readlane(my.y, j + 7));
            ushort4 q0 = *(const ushort4*)(cat + (size_t)s0 * 2 * DIM + c4);
            ushort4 q1 = *(const ushort4*)(cat + (size_t)s1 * 2 * DIM + c4);
            ushort4 q2 = *(const ushort4*)(cat + (size_t)s2 * 2 * DIM + c4);
            ushort4 q3 = *(const ushort4*)(cat + (size_t)s3 * 2 * DIM + c4);
            ushort4 q4 = *(const ushort4*)(cat + (size_t)s4 * 2 * DIM + c4);
            ushort4 q5 = *(const ushort4*)(cat + (size_t)s5 * 2 * DIM + c4);
            ushort4 q6 = *(const ushort4*)(cat + (size_t)s6 * 2 * DIM + c4);
            ushort4 q7 = *(const ushort4*)(cat + (size_t)s7 * 2 * DIM + c4);
            a0.x += v0 * bf2f(q0.x); a0.y += v0 * bf2f(q0.y);
            a0.z += v0 * bf2f(q0.z); a0.w += v0 * bf2f(q0.w);
            a1.x += v1 * bf2f(q1.x); a1.y += v1 * bf2f(q1.y);
            a1.z += v1 * bf2f(q1.z); a1.w += v1 * bf2f(q1.w);
            a2.x += v2 * bf2f(q2.x); a2.y += v2 * bf2f(q2.y);
            a2.z += v2 * bf2f(q2.z); a2.w += v2 * bf2f(q2.w);
            a3.x += v3 * bf2f(q3.x); a3.y += v3 * bf2f(q3.y);
            a3.z += v3 * bf2f(q3.z); a3.w += v3 * bf2f(q3.w);
            a4.x += v4 * bf2f(q4.x); a4.y += v4 * bf2f(q4.y);
            a4.z += v4 * bf2f(q4.z); a4.w += v4 * bf2f(q4.w);
            a5.x += v5 * bf2f(q5.x); a5.y += v5 * bf2f(q5.y);
            a5.z += v5 * bf2f(q5.z); a5.w += v5 * bf2f(q5.w);
            a6.x += v6 * bf2f(q6.x); a6.y += v6 * bf2f(q6.y);
            a6.z += v6 * bf2f(q6.z); a6.w += v6 * bf2f(q6.w);
            a7.x += v7 * bf2f(q7.x); a7.y += v7 * bf2f(q7.y);
            a7.z += v7 * bf2f(q7.z); a7.w += v7 * bf2f(q7.w);
        }
        for (; j < m; ++j) {
            int   s0 = __builtin_amdgcn_readlane(my.x, j);
            float v0 = __int_as_float(__builtin_amdgcn_readlane(my.y, j));
            ushort4 q0 = *(const ushort4*)(cat + (size_t)s0 * 2 * DIM + c4);
            a0.x += v0 * bf2f(q0.x); a0.y += v0 * bf2f(q0.y);
            a0.z += v0 * bf2f(q0.z); a0.w += v0 * bf2f(q0.w);
        }
    }
    ushort4 o;
    o.x = f2bf(((a0.x + a1.x) + (a2.x + a3.x)) + ((a4.x + a5.x) + (a6.x + a7.x)));
    o.y = f2bf(((a0.y + a1.y) + (a2.y + a3.y)) + ((a4.y + a5.y) + (a6.y + a7.y)));
    o.z = f2bf(((a0.z + a1.z) + (a2.z + a3.z)) + ((a4.z + a5.z) + (a6.z + a7.z)));
    o.w = f2bf(((a0.w + a1.w) + (a2.w + a3.w)) + ((a4.w + a5.w) + (a6.w + a7.w)));
    *(ushort4*)(cat + (size_t)wid * 2 * DIM + DIM + c4) = o;
}

// ---------------------------------------------------------------------------
// LDS-tiled GEMM, 128x128 tile per block, 3-STAGE pipeline:
//   reg set (j&1) holds tile j in flight; LDS[j&1] holds tile j for MFMA.
//   iter ks: issue loads tile ks+2 -> set ks&1 (freed last iter);
//            MFMA on LDS[ks&1];
//            ds_write tile ks+1 (set (ks+1)&1, ~2 iters of load slack) -> LDS[ks&1 ^1];
//            barrier.
// 4 waves (2x2), 64x64 per wave, +8 pad rows (conflict-free frag reads).
// 72 KB LDS -> 2 blocks/CU co-resident. Bijective XCD swizzle (316 = 8*39+4).
// MODE 0: relu(acc+bias) -> bf16 hout.
// MODE 1: prelu(acc+bias) dot w2, column-reduced -> part[8][M_PAD] (fused GEMV).
// ---------------------------------------------------------------------------
#define LDSW 72   // 64 + 8 pad, elements

#define LOADT(s) { va[s][0] = *(const f32x4*)(gA);      va[s][1] = *(const f32x4*)(gA + 8); \
                   va[s][2] = *(const f32x4*)(gA + 16); va[s][3] = *(const f32x4*)(gA + 24); \
                   vb[s][0] = *(const f32x4*)(gB);      vb[s][1] = *(const f32x4*)(gB + 8); \
                   vb[s][2] = *(const f32x4*)(gB + 16); vb[s][3] = *(const f32x4*)(gB + 24); }
#define STORET(buf, s) { \
    *(f32x4*)&As[buf][woff]      = va[s][0]; *(f32x4*)&As[buf][woff + 8]  = va[s][1]; \
    *(f32x4*)&As[buf][woff + 16] = va[s][2]; *(f32x4*)&As[buf][woff + 24] = va[s][3]; \
    *(f32x4*)&Bs[buf][woff]      = vb[s][0]; *(f32x4*)&Bs[buf][woff + 8]  = vb[s][1]; \
    *(f32x4*)&Bs[buf][woff + 16] = vb[s][2]; *(f32x4*)&Bs[buf][woff + 24] = vb[s][3]; }

template <int MODE>
__global__ __launch_bounds__(256)
void k_gemm128(const unsigned short* __restrict__ A,
               const unsigned short* __restrict__ Bt,
               const float* __restrict__ bias,
               const float* __restrict__ pa,
               const float* __restrict__ w2,
               unsigned short* __restrict__ hout,
               float* __restrict__ part) {
    __shared__ unsigned short As[2][128 * LDSW];
    __shared__ unsigned short Bs[2][128 * LDSW];

    const int t    = threadIdx.x;
    const int lane = t & 63;
    const int w    = t >> 6;
    const int wr   = w >> 1, wc = w & 1;

    // bijective XCD swizzle: 316 blocks = 8 XCDs x (40,40,40,40,39,39,39,39)
    const int orig = blockIdx.x;
    const int xcd  = orig & 7, loc = orig >> 3;          // q=39, r=4
    const int swz  = (xcd < 4 ? xcd * 40 : 160 + (xcd - 4) * 39) + loc;
    const int tn   = swz & 3;                 // 4 N-tiles
    const int tm   = swz >> 2;                // 79 M-tiles
    const int gm0  = tm * 128, gn0 = tn * 128;

    // staging map: thread t loads 64 B of row (t>>1), col half (t&1)*32
    const int srow = t >> 1;
    const int scol = (t & 1) * 32;
    const unsigned short* gA = A  + (size_t)(gm0 + srow) * KDIM + scol;
    const unsigned short* gB = Bt + (size_t)(gn0 + srow) * KDIM + scol;
    const int woff = srow * LDSW + scol;

    const int r15 = lane & 15;
    const int kf  = (lane >> 4) * 8;

    f32x4 acc[4][4] = {};
    f32x4 va[2][4], vb[2][4];

    LOADT(0);                                 // tile 0
    STORET(0, 0);
    gA += 64; gB += 64;
    LOADT(1);                                 // tile 1 in flight
    __syncthreads();                          // LDS buf0 ready

    #pragma unroll
    for (int ks = 0; ks < 8; ++ks) {
        const int cur = ks & 1;
        if (ks < 6) {                         // issue loads for tile ks+2 into
            gA += 64; gB += 64;               // the set freed by last iter's write
            LOADT(cur);
        }
        #pragma unroll
        for (int kk = 0; kk < 2; ++kk) {
            bf16x8 af[4], bf[4];
            #pragma unroll
            for (int m = 0; m < 4; ++m)
                af[m] = *(const bf16x8*)&As[cur][(wr * 64 + m * 16 + r15) * LDSW + kk * 32 + kf];
            #pragma unroll
            for (int n = 0; n < 4; ++n)
                bf[n] = *(const bf16x8*)&Bs[cur][(wc * 64 + n * 16 + r15) * LDSW + kk * 32 + kf];
            #pragma unroll
            for (int m = 0; m < 4; ++m)
                #pragma unroll
                for (int n = 0; n < 4; ++n)
                    acc[m][n] = __builtin_amdgcn_mfma_f32_16x16x32_bf16(af[m], bf[n], acc[m][n], 0, 0, 0);
        }
        if (ks < 7) {                         // tile ks+1 regs -> other LDS buf
            STORET(cur ^ 1, (ks + 1) & 1);    // (loads issued ~2 iters ago)
            __syncthreads();
        }
    }

    const int rq = lane >> 4;                // C row quad
    if (MODE == 0) {
        #pragma unroll
        for (int n = 0; n < 4; ++n) {
            int c = gn0 + wc * 64 + n * 16 + r15;
            float b = bias[c];
            #pragma unroll
            for (int m = 0; m < 4; ++m) {
                #pragma unroll
                for (int i = 0; i < 4; ++i) {
                    int row = gm0 + wr * 64 + m * 16 + rq * 4 + i;
                    float v = acc[m][n][i] + b;
                    v = v > 0.f ? v : 0.f;   // NaN/garbage from pad rows -> 0
                    hout[(size_t)row * HID + c] = f2bf(v);
                }
            }
        }
    } else {
        float rsum[4][4] = {};
        #pragma unroll
        for (int n = 0; n < 4; ++n) {
            int c = gn0 + wc * 64 + n * 16 + r15;
            float b = bias[c];
            float a = pa[c];
            float wv = w2[c];
            #pragma unroll
            for (int m = 0; m < 4; ++m)
                #pragma unroll
                for (int i = 0; i < 4; ++i) {
                    float v = acc[m][n][i] + b;
                    v = v > 0.f ? v : a * v;
                    rsum[m][i] += v * wv;
                }
        }
        // reduce over the 16 column-lanes; lane&15==0 holds the sum
        #pragma unroll
        for (int m = 0; m < 4; ++m)
            #pragma unroll
            for (int i = 0; i < 4; ++i) {
                float s = rsum[m][i];
                s += __shfl_xor(s, 1);
                s += __shfl_xor(s, 2);
                s += __shfl_xor(s, 4);
                s += __shfl_xor(s, 8);
                if (r15 == 0) {
                    int row = gm0 + wr * 64 + m * 16 + rq * 4 + i;
                    part[(size_t)(tn * 2 + wc) * M_PAD + row] = s;
                }
            }
    }
}

// ---------------------------------------------------------------------------
// pred[row] = sum_j part[j][row] + b2
// ---------------------------------------------------------------------------
__global__ void k_vout(const float* __restrict__ part, const float* __restrict__ b2,
                       float* __restrict__ pred) {
    int row = blockIdx.x * blockDim.x + threadIdx.x;
    if (row >= N_NODES) return;
    float s = b2[0];
    #pragma unroll
    for (int j = 0; j < 8; ++j) s += part[(size_t)j * M_PAD + row];
    pred[row] = s;
}

extern "C" void kernel_launch(void* const* d_in, const int* in_sizes, int n_in,
                              void* d_out, int out_size, void* d_ws, size_t ws_size,
                              hipStream_t stream) {
    const float* x    = (const float*)d_in[0];
    const int*   esrc = (const int*)  d_in[1];
    const int*   edst = (const int*)  d_in[2];
    const float* eval = (const float*)d_in[3];
    const float* Wc   = (const float*)d_in[4];
    const float* bc   = (const float*)d_in[5];
    const float* W1   = (const float*)d_in[6];
    const float* b1   = (const float*)d_in[7];
    const float* pa   = (const float*)d_in[8];
    const float* W2   = (const float*)d_in[9];
    const float* b2   = (const float*)d_in[10];
    float* pred = (float*)d_out;

    // workspace layout (16B-aligned), total ~32.6 MB
    char* w = (char*)d_ws;
    int*            deg   = (int*)w;                               //     40,960 B
    int2*           ell   = (int2*)(w + 40960);                    // 10,485,760 B (10240 x 128 x 8)
    unsigned short* cat   = (unsigned short*)(w + 10526720);       // 10,354,688 B (M_PAD x 512)
    unsigned short* Wct   = (unsigned short*)(w + 20881408);       //    524,288 B
    unsigned short* W1t   = (unsigned short*)(w + 21405696);       //    524,288 B
    unsigned short* h     = (unsigned short*)(w + 21929984);       // 10,354,688 B (M_PAD x 512)
    float*          partb = (float*)(w + 32284672);                //    323,584 B (8 x M_PAD)

    // ---- zero slot counters ----
    k_zero<<<40, 256, 0, stream>>>(deg);

    // ---- fused prep (ELL scatter + cat_x + both weight transposes) ----
    k_prep<<<5798, 256, 0, stream>>>(esrc, edst, eval, deg, ell, x, cat, Wc, Wct, W1, W1t);

    // ---- gather-aggregate into cat second half ----
    k_agg<<<(N_NODES * 64 + 255) / 256, 256, 0, stream>>>(deg, ell, cat);

    // ---- tiled GEMMs: 79 M-tiles x 4 N-tiles = 316 blocks (XCD-swizzled) ----
    k_gemm128<0><<<316, 256, 0, stream>>>(cat, Wct, bc, nullptr, nullptr, h, nullptr);
    k_gemm128<1><<<316, 256, 0, stream>>>(h, W1t, b1, pa, W2, nullptr, partb);

    // ---- final partial reduce ----
    k_vout<<<(N_NODES + 255) / 256, 256, 0, stream>>>(partb, b2, pred);
}